// Round 10
// baseline (80.227 us; speedup 1.0000x reference)
//
#include <hip/hip_runtime.h>
#include <math.h>

#define NQ 10
#define NL 4
#define NGATES (NL * NQ)
#define NTHREADS 256

typedef float f32x2 __attribute__((ext_vector_type(2)));

#if __has_builtin(__builtin_amdgcn_permlane32_swap)
#define HAVE_PL32 1
#else
#define HAVE_PL32 0
#endif
#if __has_builtin(__builtin_amdgcn_permlane16_swap)
#define HAVE_PL16 1
#else
#define HAVE_PL16 0
#endif

// ---------------------------------------------------------------------------
// 10-bit state index split WAVE(1) / lane(6) / reg(3); 2 waves per batch:
//   qubit0 -> lane 4 (swizzle)   qubit1 -> lane 32 (permlane32)
//   qubit2 -> lane 16 (permlane16)  qubit3 -> WAVE bit (LDS cross-exchange)
//   qubit4 -> reg 4   qubit5 -> reg 2   qubit6 -> reg 1
//   qubit7 -> lane 8 (row_ror:8)  qubit8 -> lane 2  qubit9 -> lane 1 (DPP)
// CNOT chain absorbed by GF(2) relabel (validated R2-R9): gate (l,q) uses
// xor-mask m = K^{-l} e_q and select s = row_q(K^l); mapped to (XW,XL,XR)
// and (SW,SL,SR) below. 9 gates have W in m -> cross-wave via LDS.
// ---------------------------------------------------------------------------

// 32-bit xor-exchange by compile-time lane mask XM (validated R9)
template<int XM>
__device__ __forceinline__ float exch1(float v, bool sp32, bool sp16) {
    if constexpr (XM == 0) return v;
    int x = __float_as_int(v);
    constexpr int low = XM & 31;
    if constexpr (low == 1)       x = __builtin_amdgcn_mov_dpp(x, 0xB1, 0xF, 0xF, true);
    else if constexpr (low == 2)  x = __builtin_amdgcn_mov_dpp(x, 0x4E, 0xF, 0xF, true);
    else if constexpr (low == 3)  x = __builtin_amdgcn_mov_dpp(x, 0x1B, 0xF, 0xF, true);
    else if constexpr (low == 7)  x = __builtin_amdgcn_mov_dpp(x, 0x141, 0xF, 0xF, true);
    else if constexpr (low == 8)  x = __builtin_amdgcn_mov_dpp(x, 0x128, 0xF, 0xF, true);
    else if constexpr (low == 9)  { x = __builtin_amdgcn_mov_dpp(x, 0x128, 0xF, 0xF, true);
                                    x = __builtin_amdgcn_mov_dpp(x, 0xB1, 0xF, 0xF, true); }
    else if constexpr (low == 10) { x = __builtin_amdgcn_mov_dpp(x, 0x128, 0xF, 0xF, true);
                                    x = __builtin_amdgcn_mov_dpp(x, 0x4E, 0xF, 0xF, true); }
    else if constexpr (low == 11) { x = __builtin_amdgcn_mov_dpp(x, 0x128, 0xF, 0xF, true);
                                    x = __builtin_amdgcn_mov_dpp(x, 0x1B, 0xF, 0xF, true); }
    else if constexpr (low == 15) x = __builtin_amdgcn_mov_dpp(x, 0x140, 0xF, 0xF, true);
    else if constexpr (low == 16) {
#if HAVE_PL16
        auto r = __builtin_amdgcn_permlane16_swap((unsigned)x, (unsigned)x, false, false);
        x = sp16 ? (int)r[0] : (int)r[1];
#else
        x = __builtin_amdgcn_ds_swizzle(x, (16 << 10) | 0x1F);
#endif
    }
    else if constexpr (low != 0)  x = __builtin_amdgcn_ds_swizzle(x, (low << 10) | 0x1F);
    if constexpr ((XM & 32) != 0) {
#if HAVE_PL32
        auto r = __builtin_amdgcn_permlane32_swap((unsigned)x, (unsigned)x, false, false);
        x = sp32 ? (int)r[0] : (int)r[1];
#else
        x = __float_as_int(__shfl_xor(__int_as_float(x), 32, 64));
#endif
    }
    return __int_as_float(x);
}

template<int XM>
__device__ __forceinline__ f32x2 exch2(f32x2 v, bool sp32, bool sp16) {
    f32x2 r;
    r.x = exch1<XM>(v.x, sp32, sp16);
    r.y = exch1<XM>(v.y, sp32, sp16);
    return r;
}

// complex t = A*st + B*pst in 4 VOP3P packed-f32 ops (validated R5-R9)
__device__ __forceinline__ f32x2 cfma4(f32x2 A, f32x2 st, f32x2 B, f32x2 pst) {
    f32x2 t;
    asm("v_pk_mul_f32 %0, %1, %2 op_sel:[0,0] op_sel_hi:[0,1]\n\t"
        "v_pk_fma_f32 %0, %1, %2, %0 op_sel:[1,1,0] op_sel_hi:[1,0,1] neg_lo:[0,1,0]\n\t"
        "v_pk_fma_f32 %0, %3, %4, %0 op_sel:[0,0,0] op_sel_hi:[0,1,1]\n\t"
        "v_pk_fma_f32 %0, %3, %4, %0 op_sel:[1,1,0] op_sel_hi:[1,0,1] neg_lo:[0,1,0]"
        : "=&v"(t)
        : "v"(A), "v"(st), "v"(B), "v"(pst));
    return t;
}

__device__ __forceinline__ void mkSel(const f32x2 (&g4)[4], bool hl,
                                      f32x2& A0, f32x2& B0, f32x2& A1, f32x2& B1) {
    A0.x = hl ? g4[3].x : g4[0].x;  A0.y = hl ? g4[3].y : g4[0].y;
    B0.x = hl ? g4[2].x : g4[1].x;  B0.y = hl ? g4[2].y : g4[1].y;
    A1.x = hl ? g4[0].x : g4[3].x;  A1.y = hl ? g4[0].y : g4[3].y;
    B1.x = hl ? g4[1].x : g4[2].x;  B1.y = hl ? g4[1].y : g4[2].y;
}

// in-wave 1q gate on 8-reg state
template<int XM, int XR, int SL, int SR, int SW>
__device__ __forceinline__ void gate(f32x2 (&st)[8], const f32x2 (&g4)[4],
                                     int lane, int W, bool sp32, bool sp16) {
    int hli = (__popc(lane & SL) & 1) ^ (SW ? W : 0);
    bool hl = hli != 0;
    f32x2 A0, B0, A1, B1;
    mkSel(g4, hl, A0, B0, A1, B1);
    f32x2 pst[8];
    #pragma unroll
    for (int r = 0; r < 8; ++r) pst[r] = exch2<XM>(st[r ^ XR], sp32, sp16);
    #pragma unroll
    for (int r = 0; r < 8; ++r) {
        const bool p1 = (__builtin_popcount(r & SR) & 1) != 0;  // compile-time
        st[r] = cfma4(p1 ? A1 : A0, st[r], p1 ? B1 : B0, pst[r]);
    }
}

// cross-wave 1q gate (W in xor-mask): exchange via LDS, double-buffered.
// sb layout: [BUF][wv][lane][reg] f32x2.
template<int XL, int XR, int SL, int SR, int SW, int BUF>
__device__ __forceinline__ void xgate(f32x2 (&st)[8], const f32x2 (&g4)[4],
                                      int lane, int wv, int W, f32x2* sb) {
    f32x2* mb = sb + (((BUF * 4 + wv) * 64 + lane) * 8);
    #pragma unroll
    for (int r = 0; r < 8; ++r) mb[r] = st[r];
    __syncthreads();
    int hli = (__popc(lane & SL) & 1) ^ (SW ? W : 0);
    bool hl = hli != 0;
    f32x2 A0, B0, A1, B1;
    mkSel(g4, hl, A0, B0, A1, B1);
    const f32x2* pb = sb + (((BUF * 4 + (wv ^ 1)) * 64 + (lane ^ XL)) * 8);
    f32x2 pst[8];
    #pragma unroll
    for (int r = 0; r < 8; ++r) pst[r] = pb[r ^ XR];
    #pragma unroll
    for (int r = 0; r < 8; ++r) {
        const bool p1 = (__builtin_popcount(r & SR) & 1) != 0;
        st[r] = cfma4(p1 ? A1 : A0, st[r], p1 ? B1 : B0, pst[r]);
    }
}

// 6-stage signed butterfly: lane L ends with sum_j (-1)^{popcount(L&j)} v_j
__device__ __forceinline__ float wht6(float v, int lane, bool sp32, bool sp16) {
    float t;
    t = exch1<1>(v, sp32, sp16);   v = (lane & 1)  ? (t - v) : (v + t);
    t = exch1<2>(v, sp32, sp16);   v = (lane & 2)  ? (t - v) : (v + t);
    t = exch1<4>(v, sp32, sp16);   v = (lane & 4)  ? (t - v) : (v + t);
    t = exch1<8>(v, sp32, sp16);   v = (lane & 8)  ? (t - v) : (v + t);
    t = exch1<16>(v, sp32, sp16);  v = (lane & 16) ? (t - v) : (v + t);
    t = exch1<32>(v, sp32, sp16);  v = (lane & 32) ? (t - v) : (v + t);
    return v;
}

__global__ __launch_bounds__(NTHREADS, 4) void qlayer_kernel(
    const float* __restrict__ x,
    const float* __restrict__ qp,
    float* __restrict__ out,
    int B)
{
    __shared__ f32x2 su[NGATES][4];          // gate matrices
    __shared__ f32x2 sbuf[2][4][64][8];      // cross-wave exchange (32 KB)
    __shared__ float evb[4][10];             // per-wave output partials

    const int t = threadIdx.x;
    if (t < NGATES) {
        float w0 = qp[t * 3 + 0], w1 = qp[t * 3 + 1], w2 = qp[t * 3 + 2];
        float cx = __cosf(0.5f * w0), sx = __sinf(0.5f * w0);
        float cy = __cosf(0.5f * w1), sy = __sinf(0.5f * w1);
        float er = __cosf(0.5f * w2), ei = -__sinf(0.5f * w2);   // ez = exp(-i w2/2)
        float m00r =  cy * cx, m00i =  sy * sx;
        float m01r = -sy * cx, m01i = -cy * sx;
        float m10r =  sy * cx, m10i = -cy * sx;
        float m11r =  cy * cx, m11i = -sy * sx;
        f32x2 v;
        v.x = er * m00r - ei * m00i;  v.y = er * m00i + ei * m00r;  su[t][0] = v;
        v.x = er * m01r - ei * m01i;  v.y = er * m01i + ei * m01r;  su[t][1] = v;
        v.x = er * m10r + ei * m10i;  v.y = er * m10i - ei * m10r;  su[t][2] = v;
        v.x = er * m11r + ei * m11i;  v.y = er * m11i - ei * m11r;  su[t][3] = v;
    }
    __syncthreads();

    const int lane = t & 63;
    const int wv = t >> 6;                   // wave in block (0..3)
    const int W = wv & 1;                    // qubit-3 value of this wave's half
    const int b0 = blockIdx.x * 2 + (wv >> 1);
    const bool bok = (b0 < B);
    const int bx = bok ? b0 : 0;

    bool sp32 = false, sp16 = false;
#if HAVE_PL32
    {
        auto pr = __builtin_amdgcn_permlane32_swap((unsigned)lane, (unsigned)lane, false, false);
        sp32 = ((int)pr[0] == (lane ^ 32));
    }
#endif
#if HAVE_PL16
    {
        auto pr = __builtin_amdgcn_permlane16_swap((unsigned)lane, (unsigned)lane, false, false);
        sp16 = ((int)pr[0] == (lane ^ 16));
    }
#endif

    float c[NQ], s[NQ];
    #pragma unroll
    for (int q = 0; q < NQ; ++q) {
        float h = 0.5f * x[bx * NQ + q];
        c[q] = __cosf(h);  s[q] = __sinf(h);
    }

    // initial product state: lane bits 4->q0,32->q1,16->q2,8->q7,2->q8,1->q9;
    // W->q3; reg bits 4->q4,2->q5,1->q6.
    float lf = ((lane &  4) ? s[0] : c[0]) * ((lane & 32) ? s[1] : c[1]) *
               ((lane & 16) ? s[2] : c[2]) * (W ? s[3] : c[3]) *
               ((lane &  8) ? s[7] : c[7]) * ((lane &  2) ? s[8] : c[8]) *
               ((lane &  1) ? s[9] : c[9]);
    f32x2 st[8];
    #pragma unroll
    for (int r = 0; r < 8; ++r) {
        st[r].x = lf * ((r & 4) ? s[4] : c[4]) * ((r & 2) ? s[5] : c[5]) *
                       ((r & 1) ? s[6] : c[6]);
        st[r].y = 0.0f;
    }

    f32x2* sb = &sbuf[0][0][0][0];
#define G(L, Q, XM, XR, SLm, SRm, SWm) \
    gate<XM, XR, SLm, SRm, SWm>(st, su[(L)*NQ+(Q)], lane, W, sp32, sp16);
#define XG(L, Q, XL, XR, SLm, SRm, SWm, BUF) \
    xgate<XL, XR, SLm, SRm, SWm, BUF>(st, su[(L)*NQ+(Q)], lane, wv, W, sb);

    // layer 0: m={q}, s={q}
    G (0,0, 4,0, 4,0,0)    G (0,1, 32,0, 32,0,0)  G (0,2, 16,0, 16,0,0)
    XG(0,3, 0,0, 0,0,1, 0)
    G (0,4, 0,4, 0,4,0)    G (0,5, 0,2, 0,2,0)    G (0,6, 0,1, 0,1,0)
    G (0,7, 8,0, 8,0,0)    G (0,8, 2,0, 2,0,0)    G (0,9, 1,0, 1,0,0)
    // layer 1: m={q,q+1}, s={0..q}
    G (1,0, 36,0, 4,0,0)   G (1,1, 48,0, 36,0,0)
    XG(1,2, 16,0, 52,0,0, 1)
    XG(1,3, 0,4, 52,0,1, 0)
    G (1,4, 0,6, 52,4,1)   G (1,5, 0,3, 52,6,1)   G (1,6, 8,1, 52,7,1)
    G (1,7, 10,0, 60,7,1)  G (1,8, 3,0, 62,7,1)   G (1,9, 1,0, 63,7,1)
    // layer 2: m={q,q+2}, s={q,q-2,...}
    G (2,0, 20,0, 4,0,0)
    XG(2,1, 32,0, 32,0,0, 1)
    G (2,2, 16,4, 20,0,0)
    XG(2,3, 0,2, 32,0,1, 0)
    G (2,4, 0,5, 20,4,0)   G (2,5, 8,2, 32,2,1)   G (2,6, 2,1, 20,5,0)
    G (2,7, 9,0, 40,2,1)   G (2,8, 2,0, 22,5,0)   G (2,9, 1,0, 41,2,1)
    // layer 3: m={q..q+3}, s={q,q-1,q-4,q-5,q-8,q-9}
    XG(3,0, 52,0, 4,0,0, 1)
    XG(3,1, 48,4, 36,0,0, 0)
    XG(3,2, 16,6, 48,0,0, 1)
    XG(3,3, 0,7, 16,0,1, 0)
    G (3,4, 8,7, 4,4,1)    G (3,5, 10,3, 36,6,0)  G (3,6, 2,1, 48,3,0)
    G (3,7, 11,0, 24,1,1)  G (3,8, 3,0, 14,4,1)   G (3,9, 1,0, 39,6,0)
#undef G
#undef XG

    // epilogue: probs, reg folds (P, f4, f2, f1), 4 lane-space WHTs
    float p[8];
    #pragma unroll
    for (int r = 0; r < 8; ++r) p[r] = st[r].x * st[r].x + st[r].y * st[r].y;
    float a4[4], f4 = 0.0f;
    #pragma unroll
    for (int r = 0; r < 4; ++r) { a4[r] = p[r] + p[r + 4]; f4 += p[r] - p[r + 4]; }
    float a2[2], f2 = 0.0f;
    #pragma unroll
    for (int r = 0; r < 2; ++r) { a2[r] = a4[r] + a4[r + 2]; f2 += a4[r] - a4[r + 2]; }
    float P  = a2[0] + a2[1];
    float f1 = a2[0] - a2[1];

    float wP = wht6(P,  lane, sp32, sp16);
    float w4 = wht6(f4, lane, sp32, sp16);
    float w2 = wht6(f2, lane, sp32, sp16);
    float w1 = wht6(f1, lane, sp32, sp16);

    // output rows K^4: {i,i-4,i-8} -> (fold, lane, Wsign):
    // ev0:wP@4 ev1:wP@32 ev2:wP@16 ev3:wP@0(-W) ev4:w4@4 ev5:w2@32
    // ev6:w1@16 ev7:wP@8(-W) ev8:w4@6 ev9:w2@33
    if (lane ==  4) { evb[wv][0] = wP; evb[wv][4] = w4; }
    if (lane == 32) { evb[wv][1] = wP; evb[wv][5] = w2; }
    if (lane == 16) { evb[wv][2] = wP; evb[wv][6] = w1; }
    if (lane ==  0) { evb[wv][3] = wP; }
    if (lane ==  8) { evb[wv][7] = wP; }
    if (lane ==  6) { evb[wv][8] = w4; }
    if (lane == 33) { evb[wv][9] = w2; }
    __syncthreads();

    if (bok && (wv & 1) == 0 && lane < NQ) {
        float sgn = (lane == 3 || lane == 7) ? -1.0f : 1.0f;
        out[b0 * NQ + lane] = evb[wv][lane] + sgn * evb[wv + 1][lane];
    }
}

extern "C" void kernel_launch(void* const* d_in, const int* in_sizes, int n_in,
                              void* d_out, int out_size, void* d_ws, size_t ws_size,
                              hipStream_t stream) {
    const float* x  = (const float*)d_in[0];
    const float* qp = (const float*)d_in[1];
    float* out = (float*)d_out;
    const int B = in_sizes[0] / NQ;
    const int blocks = (B + 1) / 2;           // 2 batches per block (2 waves each)
    qlayer_kernel<<<blocks, NTHREADS, 0, stream>>>(x, qp, out, B);
}

// Round 11
// 77.462 us; speedup vs baseline: 1.0357x; 1.0357x over previous
//
#include <hip/hip_runtime.h>
#include <math.h>

#define NQ 10
#define NL 4
#define NGATES (NL * NQ)
#define NTHREADS 256

typedef float f32x2 __attribute__((ext_vector_type(2)));

#if __has_builtin(__builtin_amdgcn_permlane32_swap)
#define HAVE_PL32 1
#else
#define HAVE_PL32 0
#endif
#if __has_builtin(__builtin_amdgcn_permlane16_swap)
#define HAVE_PL16 1
#else
#define HAVE_PL16 0
#endif

// ---------------------------------------------------------------------------
// 10-bit state index split WAVE(1) / lane(6) / reg(3); 2 waves per batch:
//   qubit0 -> lane 4 (swizzle)   qubit1 -> lane 32 (permlane32)
//   qubit2 -> lane 16 (permlane16)  qubit3 -> WAVE bit (LDS cross-exchange)
//   qubit4 -> reg 4   qubit5 -> reg 2   qubit6 -> reg 1
//   qubit7 -> lane 8 (row_ror:8)  qubit8 -> lane 2  qubit9 -> lane 1 (DPP)
// GF(2) relabel (validated R2-R9): gate (l,q) uses m = K^{-l} e_q,
// s = row_q(K^l). R10 bug fixed: layer-3 q6 XM=11 (was 2).
// Cross-wave LDS buffer transposed to [BUF][r][wv][lane] (R10 layout was a
// 32-way bank conflict: 64B lane stride -> 2 banks).
// ---------------------------------------------------------------------------

// 32-bit xor-exchange by compile-time lane mask XM (validated R9)
template<int XM>
__device__ __forceinline__ float exch1(float v, bool sp32, bool sp16) {
    if constexpr (XM == 0) return v;
    int x = __float_as_int(v);
    constexpr int low = XM & 31;
    if constexpr (low == 1)       x = __builtin_amdgcn_mov_dpp(x, 0xB1, 0xF, 0xF, true);
    else if constexpr (low == 2)  x = __builtin_amdgcn_mov_dpp(x, 0x4E, 0xF, 0xF, true);
    else if constexpr (low == 3)  x = __builtin_amdgcn_mov_dpp(x, 0x1B, 0xF, 0xF, true);
    else if constexpr (low == 7)  x = __builtin_amdgcn_mov_dpp(x, 0x141, 0xF, 0xF, true);
    else if constexpr (low == 8)  x = __builtin_amdgcn_mov_dpp(x, 0x128, 0xF, 0xF, true);
    else if constexpr (low == 9)  { x = __builtin_amdgcn_mov_dpp(x, 0x128, 0xF, 0xF, true);
                                    x = __builtin_amdgcn_mov_dpp(x, 0xB1, 0xF, 0xF, true); }
    else if constexpr (low == 10) { x = __builtin_amdgcn_mov_dpp(x, 0x128, 0xF, 0xF, true);
                                    x = __builtin_amdgcn_mov_dpp(x, 0x4E, 0xF, 0xF, true); }
    else if constexpr (low == 11) { x = __builtin_amdgcn_mov_dpp(x, 0x128, 0xF, 0xF, true);
                                    x = __builtin_amdgcn_mov_dpp(x, 0x1B, 0xF, 0xF, true); }
    else if constexpr (low == 15) x = __builtin_amdgcn_mov_dpp(x, 0x140, 0xF, 0xF, true);
    else if constexpr (low == 16) {
#if HAVE_PL16
        auto r = __builtin_amdgcn_permlane16_swap((unsigned)x, (unsigned)x, false, false);
        x = sp16 ? (int)r[0] : (int)r[1];
#else
        x = __builtin_amdgcn_ds_swizzle(x, (16 << 10) | 0x1F);
#endif
    }
    else if constexpr (low != 0)  x = __builtin_amdgcn_ds_swizzle(x, (low << 10) | 0x1F);
    if constexpr ((XM & 32) != 0) {
#if HAVE_PL32
        auto r = __builtin_amdgcn_permlane32_swap((unsigned)x, (unsigned)x, false, false);
        x = sp32 ? (int)r[0] : (int)r[1];
#else
        x = __float_as_int(__shfl_xor(__int_as_float(x), 32, 64));
#endif
    }
    return __int_as_float(x);
}

template<int XM>
__device__ __forceinline__ f32x2 exch2(f32x2 v, bool sp32, bool sp16) {
    f32x2 r;
    r.x = exch1<XM>(v.x, sp32, sp16);
    r.y = exch1<XM>(v.y, sp32, sp16);
    return r;
}

// complex t = A*st + B*pst in 4 VOP3P packed-f32 ops (validated R5-R10)
__device__ __forceinline__ f32x2 cfma4(f32x2 A, f32x2 st, f32x2 B, f32x2 pst) {
    f32x2 t;
    asm("v_pk_mul_f32 %0, %1, %2 op_sel:[0,0] op_sel_hi:[0,1]\n\t"
        "v_pk_fma_f32 %0, %1, %2, %0 op_sel:[1,1,0] op_sel_hi:[1,0,1] neg_lo:[0,1,0]\n\t"
        "v_pk_fma_f32 %0, %3, %4, %0 op_sel:[0,0,0] op_sel_hi:[0,1,1]\n\t"
        "v_pk_fma_f32 %0, %3, %4, %0 op_sel:[1,1,0] op_sel_hi:[1,0,1] neg_lo:[0,1,0]"
        : "=&v"(t)
        : "v"(A), "v"(st), "v"(B), "v"(pst));
    return t;
}

__device__ __forceinline__ void mkSel(const f32x2 (&g4)[4], bool hl,
                                      f32x2& A0, f32x2& B0, f32x2& A1, f32x2& B1) {
    A0.x = hl ? g4[3].x : g4[0].x;  A0.y = hl ? g4[3].y : g4[0].y;
    B0.x = hl ? g4[2].x : g4[1].x;  B0.y = hl ? g4[2].y : g4[1].y;
    A1.x = hl ? g4[0].x : g4[3].x;  A1.y = hl ? g4[0].y : g4[3].y;
    B1.x = hl ? g4[1].x : g4[2].x;  B1.y = hl ? g4[1].y : g4[2].y;
}

// in-wave 1q gate on 8-reg state
template<int XM, int XR, int SL, int SR, int SW>
__device__ __forceinline__ void gate(f32x2 (&st)[8], const f32x2 (&g4)[4],
                                     int lane, int W, bool sp32, bool sp16) {
    int hli = (__popc(lane & SL) & 1) ^ (SW ? W : 0);
    bool hl = hli != 0;
    f32x2 A0, B0, A1, B1;
    mkSel(g4, hl, A0, B0, A1, B1);
    f32x2 pst[8];
    #pragma unroll
    for (int r = 0; r < 8; ++r) pst[r] = exch2<XM>(st[r ^ XR], sp32, sp16);
    #pragma unroll
    for (int r = 0; r < 8; ++r) {
        const bool p1 = (__builtin_popcount(r & SR) & 1) != 0;  // compile-time
        st[r] = cfma4(p1 ? A1 : A0, st[r], p1 ? B1 : B0, pst[r]);
    }
}

// cross-wave 1q gate (W in xor-mask): exchange via LDS, double-buffered.
// sb layout: [BUF][r][wv][lane] f32x2 -> lane stride 8B, conflict-free.
template<int XL, int XR, int SL, int SR, int SW, int BUF>
__device__ __forceinline__ void xgate(f32x2 (&st)[8], const f32x2 (&g4)[4],
                                      int lane, int wv, int W, f32x2* sb) {
    #pragma unroll
    for (int r = 0; r < 8; ++r)
        sb[((BUF * 8 + r) * 4 + wv) * 64 + lane] = st[r];
    __syncthreads();
    int hli = (__popc(lane & SL) & 1) ^ (SW ? W : 0);
    bool hl = hli != 0;
    f32x2 A0, B0, A1, B1;
    mkSel(g4, hl, A0, B0, A1, B1);
    f32x2 pst[8];
    #pragma unroll
    for (int r = 0; r < 8; ++r)
        pst[r] = sb[((BUF * 8 + (r ^ XR)) * 4 + (wv ^ 1)) * 64 + (lane ^ XL)];
    #pragma unroll
    for (int r = 0; r < 8; ++r) {
        const bool p1 = (__builtin_popcount(r & SR) & 1) != 0;
        st[r] = cfma4(p1 ? A1 : A0, st[r], p1 ? B1 : B0, pst[r]);
    }
}

// 6-stage signed butterfly: lane L ends with sum_j (-1)^{popcount(L&j)} v_j
__device__ __forceinline__ float wht6(float v, int lane, bool sp32, bool sp16) {
    float t;
    t = exch1<1>(v, sp32, sp16);   v = (lane & 1)  ? (t - v) : (v + t);
    t = exch1<2>(v, sp32, sp16);   v = (lane & 2)  ? (t - v) : (v + t);
    t = exch1<4>(v, sp32, sp16);   v = (lane & 4)  ? (t - v) : (v + t);
    t = exch1<8>(v, sp32, sp16);   v = (lane & 8)  ? (t - v) : (v + t);
    t = exch1<16>(v, sp32, sp16);  v = (lane & 16) ? (t - v) : (v + t);
    t = exch1<32>(v, sp32, sp16);  v = (lane & 32) ? (t - v) : (v + t);
    return v;
}

__global__ __launch_bounds__(NTHREADS, 4) void qlayer_kernel(
    const float* __restrict__ x,
    const float* __restrict__ qp,
    float* __restrict__ out,
    int B)
{
    __shared__ f32x2 su[NGATES][4];          // gate matrices
    __shared__ f32x2 sbuf[2][8][4][64];      // cross-wave exchange (32 KB)
    __shared__ float evb[4][10];             // per-wave output partials

    const int t = threadIdx.x;
    if (t < NGATES) {
        float w0 = qp[t * 3 + 0], w1 = qp[t * 3 + 1], w2 = qp[t * 3 + 2];
        float cx = __cosf(0.5f * w0), sx = __sinf(0.5f * w0);
        float cy = __cosf(0.5f * w1), sy = __sinf(0.5f * w1);
        float er = __cosf(0.5f * w2), ei = -__sinf(0.5f * w2);   // ez = exp(-i w2/2)
        float m00r =  cy * cx, m00i =  sy * sx;
        float m01r = -sy * cx, m01i = -cy * sx;
        float m10r =  sy * cx, m10i = -cy * sx;
        float m11r =  cy * cx, m11i = -sy * sx;
        f32x2 v;
        v.x = er * m00r - ei * m00i;  v.y = er * m00i + ei * m00r;  su[t][0] = v;
        v.x = er * m01r - ei * m01i;  v.y = er * m01i + ei * m01r;  su[t][1] = v;
        v.x = er * m10r + ei * m10i;  v.y = er * m10i - ei * m10r;  su[t][2] = v;
        v.x = er * m11r + ei * m11i;  v.y = er * m11i - ei * m11r;  su[t][3] = v;
    }
    __syncthreads();

    const int lane = t & 63;
    const int wv = t >> 6;                   // wave in block (0..3)
    const int W = wv & 1;                    // qubit-3 value of this wave's half
    const int b0 = blockIdx.x * 2 + (wv >> 1);
    const bool bok = (b0 < B);
    const int bx = bok ? b0 : 0;

    bool sp32 = false, sp16 = false;
#if HAVE_PL32
    {
        auto pr = __builtin_amdgcn_permlane32_swap((unsigned)lane, (unsigned)lane, false, false);
        sp32 = ((int)pr[0] == (lane ^ 32));
    }
#endif
#if HAVE_PL16
    {
        auto pr = __builtin_amdgcn_permlane16_swap((unsigned)lane, (unsigned)lane, false, false);
        sp16 = ((int)pr[0] == (lane ^ 16));
    }
#endif

    float c[NQ], s[NQ];
    #pragma unroll
    for (int q = 0; q < NQ; ++q) {
        float h = 0.5f * x[bx * NQ + q];
        c[q] = __cosf(h);  s[q] = __sinf(h);
    }

    // initial product state: lane bits 4->q0,32->q1,16->q2,8->q7,2->q8,1->q9;
    // W->q3; reg bits 4->q4,2->q5,1->q6.
    float lf = ((lane &  4) ? s[0] : c[0]) * ((lane & 32) ? s[1] : c[1]) *
               ((lane & 16) ? s[2] : c[2]) * (W ? s[3] : c[3]) *
               ((lane &  8) ? s[7] : c[7]) * ((lane &  2) ? s[8] : c[8]) *
               ((lane &  1) ? s[9] : c[9]);
    f32x2 st[8];
    #pragma unroll
    for (int r = 0; r < 8; ++r) {
        st[r].x = lf * ((r & 4) ? s[4] : c[4]) * ((r & 2) ? s[5] : c[5]) *
                       ((r & 1) ? s[6] : c[6]);
        st[r].y = 0.0f;
    }

    f32x2* sb = &sbuf[0][0][0][0];
#define G(L, Q, XM, XR, SLm, SRm, SWm) \
    gate<XM, XR, SLm, SRm, SWm>(st, su[(L)*NQ+(Q)], lane, W, sp32, sp16);
#define XG(L, Q, XL, XR, SLm, SRm, SWm, BUF) \
    xgate<XL, XR, SLm, SRm, SWm, BUF>(st, su[(L)*NQ+(Q)], lane, wv, W, sb);

    // layer 0: m={q}, s={q}
    G (0,0, 4,0, 4,0,0)    G (0,1, 32,0, 32,0,0)  G (0,2, 16,0, 16,0,0)
    XG(0,3, 0,0, 0,0,1, 0)
    G (0,4, 0,4, 0,4,0)    G (0,5, 0,2, 0,2,0)    G (0,6, 0,1, 0,1,0)
    G (0,7, 8,0, 8,0,0)    G (0,8, 2,0, 2,0,0)    G (0,9, 1,0, 1,0,0)
    // layer 1: m={q,q+1}, s={0..q}
    G (1,0, 36,0, 4,0,0)   G (1,1, 48,0, 36,0,0)
    XG(1,2, 16,0, 52,0,0, 1)
    XG(1,3, 0,4, 52,0,1, 0)
    G (1,4, 0,6, 52,4,1)   G (1,5, 0,3, 52,6,1)   G (1,6, 8,1, 52,7,1)
    G (1,7, 10,0, 60,7,1)  G (1,8, 3,0, 62,7,1)   G (1,9, 1,0, 63,7,1)
    // layer 2: m={q,q+2}, s={q,q-2,...}
    G (2,0, 20,0, 4,0,0)
    XG(2,1, 32,0, 32,0,0, 1)
    G (2,2, 16,4, 20,0,0)
    XG(2,3, 0,2, 32,0,1, 0)
    G (2,4, 0,5, 20,4,0)   G (2,5, 8,2, 32,2,1)   G (2,6, 2,1, 20,5,0)
    G (2,7, 9,0, 40,2,1)   G (2,8, 2,0, 22,5,0)   G (2,9, 1,0, 41,2,1)
    // layer 3: m={q..q+3}, s={q,q-1,q-4,q-5,q-8,q-9}
    XG(3,0, 52,0, 4,0,0, 1)
    XG(3,1, 48,4, 36,0,0, 0)
    XG(3,2, 16,6, 48,0,0, 1)
    XG(3,3, 0,7, 16,0,1, 0)
    G (3,4, 8,7, 4,4,1)    G (3,5, 10,3, 36,6,0)  G (3,6, 11,1, 48,3,0)
    G (3,7, 11,0, 24,1,1)  G (3,8, 3,0, 14,4,1)   G (3,9, 1,0, 39,6,0)
#undef G
#undef XG

    // epilogue: probs, reg folds (P, f4, f2, f1), 4 lane-space WHTs
    float p[8];
    #pragma unroll
    for (int r = 0; r < 8; ++r) p[r] = st[r].x * st[r].x + st[r].y * st[r].y;
    float a4[4], f4 = 0.0f;
    #pragma unroll
    for (int r = 0; r < 4; ++r) { a4[r] = p[r] + p[r + 4]; f4 += p[r] - p[r + 4]; }
    float a2[2], f2 = 0.0f;
    #pragma unroll
    for (int r = 0; r < 2; ++r) { a2[r] = a4[r] + a4[r + 2]; f2 += a4[r] - a4[r + 2]; }
    float P  = a2[0] + a2[1];
    float f1 = a2[0] - a2[1];

    float wP = wht6(P,  lane, sp32, sp16);
    float w4 = wht6(f4, lane, sp32, sp16);
    float w2 = wht6(f2, lane, sp32, sp16);
    float w1 = wht6(f1, lane, sp32, sp16);

    // output rows K^4: {i,i-4,i-8} -> (fold, lane, Wsign):
    // ev0:wP@4 ev1:wP@32 ev2:wP@16 ev3:wP@0(-W) ev4:w4@4 ev5:w2@32
    // ev6:w1@16 ev7:wP@8(-W) ev8:w4@6 ev9:w2@33
    if (lane ==  4) { evb[wv][0] = wP; evb[wv][4] = w4; }
    if (lane == 32) { evb[wv][1] = wP; evb[wv][5] = w2; }
    if (lane == 16) { evb[wv][2] = wP; evb[wv][6] = w1; }
    if (lane ==  0) { evb[wv][3] = wP; }
    if (lane ==  8) { evb[wv][7] = wP; }
    if (lane ==  6) { evb[wv][8] = w4; }
    if (lane == 33) { evb[wv][9] = w2; }
    __syncthreads();

    if (bok && (wv & 1) == 0 && lane < NQ) {
        float sgn = (lane == 3 || lane == 7) ? -1.0f : 1.0f;
        out[b0 * NQ + lane] = evb[wv][lane] + sgn * evb[wv + 1][lane];
    }
}

extern "C" void kernel_launch(void* const* d_in, const int* in_sizes, int n_in,
                              void* d_out, int out_size, void* d_ws, size_t ws_size,
                              hipStream_t stream) {
    const float* x  = (const float*)d_in[0];
    const float* qp = (const float*)d_in[1];
    float* out = (float*)d_out;
    const int B = in_sizes[0] / NQ;
    const int blocks = (B + 1) / 2;           // 2 batches per block (2 waves each)
    qlayer_kernel<<<blocks, NTHREADS, 0, stream>>>(x, qp, out, B);
}